// Round 1
// baseline (16068.230 us; speedup 1.0000x reference)
//
#include <hip/hip_runtime.h>

typedef unsigned short ushort_t;
typedef __attribute__((ext_vector_type(8))) short short8;
typedef __attribute__((ext_vector_type(4))) float f32x4;

#define SEQ 512
#define BATCH 32
#define HID 1024
#define NGATE 4
#define GCOLS 4096           // 4*HID
#define MROWS 16384          // SEQ*BATCH
#define HSEQ_ELEMS 16777216  // SEQ*BATCH*HID

__device__ __forceinline__ ushort_t f2bf(float f) {
    unsigned u = __float_as_uint(f);
    unsigned r = (u + 0x7FFFu + ((u >> 16) & 1u)) >> 16;
    return (ushort_t)r;
}
__device__ __forceinline__ float bf2f(ushort_t u) {
    return __uint_as_float(((unsigned)u) << 16);
}
__device__ __forceinline__ float sigmoidf_(float x) { return 1.f / (1.f + __expf(-x)); }
__device__ __forceinline__ float tanhs_(float x) {
    float ax = fabsf(x);
    float e  = __expf(-2.f * ax);
    float t  = (1.f - e) / (1.f + e);
    return copysignf(t, x);
}

// ---------------- convert x (fp32 -> bf16) ----------------
__global__ __launch_bounds__(256) void k_convert_x(const float* __restrict__ x, ushort_t* __restrict__ xbf) {
    size_t i = ((size_t)blockIdx.x * 256 + threadIdx.x) * 8;
    float4 a = *(const float4*)(x + i);
    float4 b = *(const float4*)(x + i + 4);
    short8 v;
    v[0] = (short)f2bf(a.x); v[1] = (short)f2bf(a.y); v[2] = (short)f2bf(a.z); v[3] = (short)f2bf(a.w);
    v[4] = (short)f2bf(b.x); v[5] = (short)f2bf(b.y); v[6] = (short)f2bf(b.z); v[7] = (short)f2bf(b.w);
    *(short8*)(xbf + i) = v;
}

// ---------------- transpose-convert 8 square matrices (U_i..o, V_i..o) ----------------
// dst[n][k] = src[k][n], fp32 -> bf16.  UT/VT laid out [gate][1024 n][1024 k].
__global__ __launch_bounds__(256) void k_transpose8(
    const float* __restrict__ u0, const float* __restrict__ u1, const float* __restrict__ u2, const float* __restrict__ u3,
    const float* __restrict__ v0, const float* __restrict__ v1, const float* __restrict__ v2, const float* __restrict__ v3,
    ushort_t* __restrict__ UT, ushort_t* __restrict__ VT) {
    __shared__ float tile[32][33];
    int m  = blockIdx.x >> 10;    // matrix 0..7
    int tl = blockIdx.x & 1023;
    int tr = tl >> 5, tc = tl & 31;
    const float* src = (m == 0) ? u0 : (m == 1) ? u1 : (m == 2) ? u2 : (m == 3) ? u3
                      : (m == 4) ? v0 : (m == 5) ? v1 : (m == 6) ? v2 : v3;
    int r = threadIdx.x >> 5, c = threadIdx.x & 31;
    int k0 = tr * 32, n0 = tc * 32;
#pragma unroll
    for (int i = 0; i < 4; ++i)
        tile[r + 8 * i][c] = src[(size_t)(k0 + r + 8 * i) * HID + n0 + c];
    __syncthreads();
    ushort_t* dst = (m < 4) ? (UT + (size_t)m * HID * HID) : (VT + (size_t)(m - 4) * HID * HID);
#pragma unroll
    for (int i = 0; i < 4; ++i) {
        int row = r + 8 * i;
        dst[(size_t)(n0 + row) * HID + k0 + c] = f2bf(tile[c][row]);
    }
}

// ---------------- phase-1 GEMM: gates_pre[m, gcol] = sum_k x_bf[m,k] * UT[gcol,k] + bias ----------------
// 128x128 tile, BK=64, 4 waves (2x2), 16x16x32 bf16 MFMA. Output bf16.
__global__ __launch_bounds__(256) void k_gemm(
    const ushort_t* __restrict__ A, const ushort_t* __restrict__ Bt,
    const float* __restrict__ pbi, const float* __restrict__ pbf,
    const float* __restrict__ pbc, const float* __restrict__ pbo,
    ushort_t* __restrict__ gates) {
    __shared__ ushort_t As[128 * 64];
    __shared__ ushort_t Bs[128 * 64];
    const int tid = threadIdx.x, lane = tid & 63, wv = tid >> 6;
    const int bm = blockIdx.x & 127, bn = blockIdx.x >> 7;
    const size_t m0 = (size_t)bm * 128;
    const size_t n0 = (size_t)bn * 128;
    const int wm = wv >> 1, wn = wv & 1;
    f32x4 acc[4][4] = {};
    const int srow = tid >> 1, skof = (tid & 1) * 32;
    const ushort_t* ap = A + (m0 + srow) * 1024 + skof;
    const ushort_t* bp = Bt + (n0 + srow) * 1024 + skof;

    for (int kt = 0; kt < 16; ++kt) {
        int k0 = kt * 64;
#pragma unroll
        for (int i = 0; i < 4; ++i) {
            *(short8*)(&As[srow * 64 + skof + i * 8]) = *(const short8*)(ap + k0 + i * 8);
            *(short8*)(&Bs[srow * 64 + skof + i * 8]) = *(const short8*)(bp + k0 + i * 8);
        }
        __syncthreads();
#pragma unroll
        for (int kk = 0; kk < 64; kk += 32) {
            short8 af[4], bfr[4];
            int ko = kk + (lane >> 4) * 8;
#pragma unroll
            for (int mi = 0; mi < 4; ++mi) af[mi] = *(const short8*)(&As[(wm * 64 + mi * 16 + (lane & 15)) * 64 + ko]);
#pragma unroll
            for (int ni = 0; ni < 4; ++ni) bfr[ni] = *(const short8*)(&Bs[(wn * 64 + ni * 16 + (lane & 15)) * 64 + ko]);
#pragma unroll
            for (int mi = 0; mi < 4; ++mi)
#pragma unroll
                for (int ni = 0; ni < 4; ++ni)
                    acc[mi][ni] = __builtin_amdgcn_mfma_f32_16x16x32_bf16(af[mi], bfr[ni], acc[mi][ni], 0, 0, 0);
        }
        __syncthreads();
    }
    const int g = (int)(n0 >> 10);
    const float* bias = (g == 0) ? pbi : (g == 1) ? pbf : (g == 2) ? pbc : pbo;
#pragma unroll
    for (int ni = 0; ni < 4; ++ni) {
        int col = (int)n0 + wn * 64 + ni * 16 + (lane & 15);
        float bv = bias[col & 1023];
#pragma unroll
        for (int mi = 0; mi < 4; ++mi) {
            int row0 = (int)m0 + wm * 64 + mi * 16 + ((lane >> 4) << 2);
#pragma unroll
            for (int r = 0; r < 4; ++r)
                gates[(size_t)(row0 + r) * GCOLS + col] = f2bf(acc[mi][ni][r] + bv);
        }
    }
}

// ---------------- grid barrier: flag array, release store + relaxed polls + acquire fence ----------------
__device__ __forceinline__ void gbar(unsigned* flags, int wgid, unsigned val) {
    __syncthreads();
    if (threadIdx.x == 0) {
        __threadfence();  // belt & suspenders: flush prior stores (wbl2)
        __hip_atomic_store(&flags[wgid], val, __ATOMIC_RELEASE, __HIP_MEMORY_SCOPE_AGENT);
    }
    if (threadIdx.x < 64) {
        const int l = threadIdx.x;
        for (;;) {
            unsigned f0 = __hip_atomic_load(&flags[l], __ATOMIC_RELAXED, __HIP_MEMORY_SCOPE_AGENT);
            unsigned f1 = __hip_atomic_load(&flags[l + 64], __ATOMIC_RELAXED, __HIP_MEMORY_SCOPE_AGENT);
            unsigned f2 = __hip_atomic_load(&flags[l + 128], __ATOMIC_RELAXED, __HIP_MEMORY_SCOPE_AGENT);
            unsigned f3 = __hip_atomic_load(&flags[l + 192], __ATOMIC_RELAXED, __HIP_MEMORY_SCOPE_AGENT);
            if (__all(f0 >= val && f1 >= val && f2 >= val && f3 >= val)) break;
            __builtin_amdgcn_s_sleep(1);
        }
    }
    __syncthreads();
    __threadfence();  // acquire: invalidate L1/L2 so fresh h is visible
}

// ---------------- persistent scan kernel: 256 WGs x 256 threads, 1 WG per CU ----------------
// WG w owns hidden columns [w*4, w*4+4) for all 4 gates. V slice resident in LDS for all 512 steps.
__global__ __launch_bounds__(256) void k_scan(
    const ushort_t* __restrict__ gates, const ushort_t* __restrict__ VT,
    ushort_t* hbuf, unsigned* flags, float* __restrict__ out) {
    __shared__ ushort_t Vs[16 * 1032];  // padded row stride breaks 16-way bank conflict
    __shared__ float red[4 * 512];
    __shared__ float pre[512];
    const int tid = threadIdx.x, w = blockIdx.x;
    const int lane = tid & 63, wv = tid >> 6;
    const int n0 = w * 4;

    // Load V slice: rows j = g*4+cl  ->  V_g[:, n0+cl] with k contiguous
#pragma unroll
    for (int it = 0; it < 8; ++it) {
        int chunk = it * 256 + tid;  // 0..2047
        int j = chunk >> 7;
        int kc = (chunk & 127) * 8;
        int g = j >> 2, cl = j & 3;
        *(short8*)(&Vs[j * 1032 + kc]) =
            *(const short8*)(VT + ((size_t)(g * 1024 + n0 + cl)) * 1024 + kc);
    }

    const int b = tid >> 2, cl = tid & 3;  // valid for tid < 128
    float c_reg = 0.f;
    if (tid < 128) hbuf[b * 1024 + n0 + cl] = 0;  // zero h buffer 0 (this WG's slice)
    gbar(flags, w, 1u);

    const int arow = lane & 15;
    const int ksub = (lane >> 4) * 8;
    const int kb = wv * 256;

    for (int t = 0; t < SEQ; ++t) {
        const ushort_t* hc = hbuf + (t & 1) * 32768;
        ushort_t* hn = hbuf + ((t & 1) ^ 1) * 32768;

        // xu loads for this step are h-independent: issue early, latency hides under MFMA
        float xi = 0.f, xf = 0.f, xc = 0.f, xo = 0.f;
        if (tid < 128) {
            size_t rb = ((size_t)(t * 32 + b)) * GCOLS + n0 + cl;
            xi = bf2f(gates[rb]);
            xf = bf2f(gates[rb + 1024]);
            xc = bf2f(gates[rb + 2048]);
            xo = bf2f(gates[rb + 3072]);
        }

        // GEMM: pre[b][j] = sum_k h[b,k] * Vs[j,k], K split 4 ways across waves
        f32x4 acc0 = {}, acc1 = {};
#pragma unroll
        for (int ks = 0; ks < 8; ++ks) {
            int k = kb + ks * 32 + ksub;
            short8 a0 = *(const short8*)(hc + arow * 1024 + k);
            short8 a1 = *(const short8*)(hc + (16 + arow) * 1024 + k);
            short8 bfr = *(const short8*)(&Vs[arow * 1032 + k]);
            acc0 = __builtin_amdgcn_mfma_f32_16x16x32_bf16(a0, bfr, acc0, 0, 0, 0);
            acc1 = __builtin_amdgcn_mfma_f32_16x16x32_bf16(a1, bfr, acc1, 0, 0, 0);
        }
        {
            float* rp = red + wv * 512;
            int rr = (lane >> 4) * 4, rc = lane & 15;
#pragma unroll
            for (int r = 0; r < 4; ++r) {
                rp[(rr + r) * 16 + rc] = acc0[r];
                rp[256 + (rr + r) * 16 + rc] = acc1[r];
            }
        }
        __syncthreads();
        {
            float s0 = red[tid] + red[512 + tid] + red[1024 + tid] + red[1536 + tid];
            float s1 = red[256 + tid] + red[768 + tid] + red[1280 + tid] + red[1792 + tid];
            pre[tid] = s0;
            pre[256 + tid] = s1;
        }
        __syncthreads();

        if (tid < 128) {
            float pi = pre[b * 16 + cl];
            float pf = pre[b * 16 + 4 + cl];
            float pc = pre[b * 16 + 8 + cl];
            float po = pre[b * 16 + 12 + cl];
            float ig = sigmoidf_(xi + pi);
            float fg = sigmoidf_(xf + pf);
            float gg = tanhs_(xc + pc);
            float og = sigmoidf_(xo + po);
            c_reg = fg * c_reg + ig * gg;
            float h = og * tanhs_(c_reg);
            out[((size_t)t * 32 + b) * 1024 + n0 + cl] = h;
            hn[b * 1024 + n0 + cl] = f2bf(h);
            if (t == SEQ - 1) {
                out[HSEQ_ELEMS + b * 1024 + n0 + cl] = h;
                out[HSEQ_ELEMS + 32768 + b * 1024 + n0 + cl] = c_reg;
            }
        }
        gbar(flags, w, (unsigned)(t + 2));
    }
}

extern "C" void kernel_launch(void* const* d_in, const int* in_sizes, int n_in,
                              void* d_out, int out_size, void* d_ws, size_t ws_size,
                              hipStream_t stream) {
    const float* x  = (const float*)d_in[0];
    const float* Ui = (const float*)d_in[1];
    const float* Vi = (const float*)d_in[2];
    const float* bi = (const float*)d_in[3];
    const float* Uf = (const float*)d_in[4];
    const float* Vf = (const float*)d_in[5];
    const float* bf = (const float*)d_in[6];
    const float* Uc = (const float*)d_in[7];
    const float* Vc = (const float*)d_in[8];
    const float* bc = (const float*)d_in[9];
    const float* Uo = (const float*)d_in[10];
    const float* Vo = (const float*)d_in[11];
    const float* bo = (const float*)d_in[12];

    char* ws = (char*)d_ws;
    unsigned* flags = (unsigned*)ws;                          // 4096 B
    ushort_t* hbuf  = (ushort_t*)(ws + 4096);                 // 131072 B (2 x 32x1024 bf16)
    ushort_t* xbf   = (ushort_t*)(ws + 135168);               // 33554432 B
    ushort_t* UT    = (ushort_t*)(ws + 33689600);             // 8388608 B
    ushort_t* VT    = (ushort_t*)(ws + 42078208);             // 8388608 B
    ushort_t* gates = (ushort_t*)(ws + 50466816);             // 134217728 B -> end ~184.7 MB

    hipMemsetAsync(flags, 0, 4096, stream);
    hipLaunchKernelGGL(k_convert_x, dim3(8192), dim3(256), 0, stream, x, xbf);
    hipLaunchKernelGGL(k_transpose8, dim3(8192), dim3(256), 0, stream,
                       Ui, Uf, Uc, Uo, Vi, Vf, Vc, Vo, UT, VT);
    hipLaunchKernelGGL(k_gemm, dim3(4096), dim3(256), 0, stream,
                       xbf, UT, bi, bf, bc, bo, gates);
    hipLaunchKernelGGL(k_scan, dim3(256), dim3(256), 0, stream,
                       gates, VT, hbuf, flags, (float*)d_out);
}

// Round 2
// 4976.391 us; speedup vs baseline: 3.2289x; 3.2289x over previous
//
#include <hip/hip_runtime.h>

typedef unsigned short ushort_t;
typedef unsigned long long u64;
typedef __attribute__((ext_vector_type(8))) short short8;
typedef __attribute__((ext_vector_type(4))) float f32x4;

#define SEQ 512
#define BATCH 32
#define HID 1024
#define GCOLS 4096           // 4*HID
#define HSEQ_ELEMS 16777216  // SEQ*BATCH*HID

__device__ __forceinline__ ushort_t f2bf(float f) {
    unsigned u = __float_as_uint(f);
    unsigned r = (u + 0x7FFFu + ((u >> 16) & 1u)) >> 16;
    return (ushort_t)r;
}
__device__ __forceinline__ float bf2f(ushort_t u) {
    return __uint_as_float(((unsigned)u) << 16);
}
__device__ __forceinline__ float sigmoidf_(float x) { return 1.f / (1.f + __expf(-x)); }
__device__ __forceinline__ float tanhs_(float x) {
    float ax = fabsf(x);
    float e  = __expf(-2.f * ax);
    float t  = (1.f - e) / (1.f + e);
    return copysignf(t, x);
}

// ---------------- convert x (fp32 -> bf16) ----------------
__global__ __launch_bounds__(256) void k_convert_x(const float* __restrict__ x, ushort_t* __restrict__ xbf) {
    size_t i = ((size_t)blockIdx.x * 256 + threadIdx.x) * 8;
    float4 a = *(const float4*)(x + i);
    float4 b = *(const float4*)(x + i + 4);
    short8 v;
    v[0] = (short)f2bf(a.x); v[1] = (short)f2bf(a.y); v[2] = (short)f2bf(a.z); v[3] = (short)f2bf(a.w);
    v[4] = (short)f2bf(b.x); v[5] = (short)f2bf(b.y); v[6] = (short)f2bf(b.z); v[7] = (short)f2bf(b.w);
    *(short8*)(xbf + i) = v;
}

// ---------------- transpose-convert 8 square matrices (U_i..o, V_i..o) ----------------
__global__ __launch_bounds__(256) void k_transpose8(
    const float* __restrict__ u0, const float* __restrict__ u1, const float* __restrict__ u2, const float* __restrict__ u3,
    const float* __restrict__ v0, const float* __restrict__ v1, const float* __restrict__ v2, const float* __restrict__ v3,
    ushort_t* __restrict__ UT, ushort_t* __restrict__ VT) {
    __shared__ float tile[32][33];
    int m  = blockIdx.x >> 10;    // matrix 0..7
    int tl = blockIdx.x & 1023;
    int tr = tl >> 5, tc = tl & 31;
    const float* src = (m == 0) ? u0 : (m == 1) ? u1 : (m == 2) ? u2 : (m == 3) ? u3
                      : (m == 4) ? v0 : (m == 5) ? v1 : (m == 6) ? v2 : v3;
    int r = threadIdx.x >> 5, c = threadIdx.x & 31;
    int k0 = tr * 32, n0 = tc * 32;
#pragma unroll
    for (int i = 0; i < 4; ++i)
        tile[r + 8 * i][c] = src[(size_t)(k0 + r + 8 * i) * HID + n0 + c];
    __syncthreads();
    ushort_t* dst = (m < 4) ? (UT + (size_t)m * HID * HID) : (VT + (size_t)(m - 4) * HID * HID);
#pragma unroll
    for (int i = 0; i < 4; ++i) {
        int row = r + 8 * i;
        dst[(size_t)(n0 + row) * HID + k0 + c] = f2bf(tile[c][row]);
    }
}

// ---------------- phase-1 GEMM: gates_pre[m, gcol] = sum_k x_bf[m,k] * UT[gcol,k] + bias ----------------
__global__ __launch_bounds__(256) void k_gemm(
    const ushort_t* __restrict__ A, const ushort_t* __restrict__ Bt,
    const float* __restrict__ pbi, const float* __restrict__ pbf,
    const float* __restrict__ pbc, const float* __restrict__ pbo,
    ushort_t* __restrict__ gates) {
    __shared__ ushort_t As[128 * 64];
    __shared__ ushort_t Bs[128 * 64];
    const int tid = threadIdx.x, lane = tid & 63, wv = tid >> 6;
    const int bm = blockIdx.x & 127, bn = blockIdx.x >> 7;
    const size_t m0 = (size_t)bm * 128;
    const size_t n0 = (size_t)bn * 128;
    const int wm = wv >> 1, wn = wv & 1;
    f32x4 acc[4][4] = {};
    const int srow = tid >> 1, skof = (tid & 1) * 32;
    const ushort_t* ap = A + (m0 + srow) * 1024 + skof;
    const ushort_t* bp = Bt + (n0 + srow) * 1024 + skof;

    for (int kt = 0; kt < 16; ++kt) {
        int k0 = kt * 64;
#pragma unroll
        for (int i = 0; i < 4; ++i) {
            *(short8*)(&As[srow * 64 + skof + i * 8]) = *(const short8*)(ap + k0 + i * 8);
            *(short8*)(&Bs[srow * 64 + skof + i * 8]) = *(const short8*)(bp + k0 + i * 8);
        }
        __syncthreads();
#pragma unroll
        for (int kk = 0; kk < 64; kk += 32) {
            short8 af[4], bfr[4];
            int ko = kk + (lane >> 4) * 8;
#pragma unroll
            for (int mi = 0; mi < 4; ++mi) af[mi] = *(const short8*)(&As[(wm * 64 + mi * 16 + (lane & 15)) * 64 + ko]);
#pragma unroll
            for (int ni = 0; ni < 4; ++ni) bfr[ni] = *(const short8*)(&Bs[(wn * 64 + ni * 16 + (lane & 15)) * 64 + ko]);
#pragma unroll
            for (int mi = 0; mi < 4; ++mi)
#pragma unroll
                for (int ni = 0; ni < 4; ++ni)
                    acc[mi][ni] = __builtin_amdgcn_mfma_f32_16x16x32_bf16(af[mi], bfr[ni], acc[mi][ni], 0, 0, 0);
        }
        __syncthreads();
    }
    const int g = (int)(n0 >> 10);
    const float* bias = (g == 0) ? pbi : (g == 1) ? pbf : (g == 2) ? pbc : pbo;
#pragma unroll
    for (int ni = 0; ni < 4; ++ni) {
        int col = (int)n0 + wn * 64 + ni * 16 + (lane & 15);
        float bv = bias[col & 1023];
#pragma unroll
        for (int mi = 0; mi < 4; ++mi) {
            int row0 = (int)m0 + wm * 64 + mi * 16 + ((lane >> 4) << 2);
#pragma unroll
            for (int r = 0; r < 4; ++r)
                gates[(size_t)(row0 + r) * GCOLS + col] = f2bf(acc[mi][ni][r] + bv);
        }
    }
}

// ---------------- persistent scan kernel: 256 WGs x 256 threads, 1 WG per CU ----------------
// Fence-free cross-XCD protocol: all cross-WG data (h double-buffer, flags) moves through
// agent-scope relaxed atomics (sc1 -> device coherence point / L3). No threadfence anywhere.
// V fragments live in registers for the whole scan (identical every step).
__global__ __launch_bounds__(256) void k_scan(
    const ushort_t* __restrict__ gates, const ushort_t* __restrict__ VT,
    ushort_t* hbuf, unsigned* flags, float* __restrict__ out) {
    __shared__ float red[4 * 512];
    __shared__ float pre[512];
    __shared__ ushort_t hsh[128];
    const int tid = threadIdx.x, w = blockIdx.x;
    const int lane = tid & 63, wv = tid >> 6;
    const int n0 = w * 4;
    const int arow = lane & 15;          // MFMA row (batch row within 16-block / V slice row)
    const int ksub = (lane >> 4) * 8;
    const int kb = wv * 256;             // K split 4 ways across waves
    const int vg = arow >> 2, vcl = arow & 3;

    // V fragments: resident in 32 VGPRs for all 512 steps (plain cached loads, V is constant)
    short8 bv[8];
    {
        const ushort_t* vrow = VT + ((size_t)(vg * 1024 + n0 + vcl)) * 1024 + kb + ksub;
#pragma unroll
        for (int ks = 0; ks < 8; ++ks)
            bv[ks] = *(const short8*)(vrow + ks * 32);
    }

    const int b = tid >> 2, cl = tid & 3;  // valid for tid < 128
    float c_reg = 0.f;

    // zero h buffer 0 (this WG's 4-col slice), sc1 stores from wave 0 only
    if (tid < 32)
        __hip_atomic_store((u64*)(hbuf + tid * 1024 + n0), (u64)0,
                           __ATOMIC_RELAXED, __HIP_MEMORY_SCOPE_AGENT);
    // barrier (val=1): wave-0 stores drained by wave-0 waitcnt, then flag + poll
    if (wv == 0) {
        asm volatile("s_waitcnt vmcnt(0)" ::: "memory");
        if (lane == 0)
            __hip_atomic_store(&flags[w], 1u, __ATOMIC_RELAXED, __HIP_MEMORY_SCOPE_AGENT);
        for (;;) {
            unsigned f0 = __hip_atomic_load(&flags[lane], __ATOMIC_RELAXED, __HIP_MEMORY_SCOPE_AGENT);
            unsigned f1 = __hip_atomic_load(&flags[lane + 64], __ATOMIC_RELAXED, __HIP_MEMORY_SCOPE_AGENT);
            unsigned f2 = __hip_atomic_load(&flags[lane + 128], __ATOMIC_RELAXED, __HIP_MEMORY_SCOPE_AGENT);
            unsigned f3 = __hip_atomic_load(&flags[lane + 192], __ATOMIC_RELAXED, __HIP_MEMORY_SCOPE_AGENT);
            if (__all(f0 >= 1u && f1 >= 1u && f2 >= 1u && f3 >= 1u)) break;
            __builtin_amdgcn_s_sleep(1);
        }
    }
    __syncthreads();

    for (int t = 0; t < SEQ; ++t) {
        const ushort_t* hc = hbuf + (t & 1) * 32768;
        ushort_t* hn = hbuf + ((t & 1) ^ 1) * 32768;

        // gates loads: h-independent, cached path, issue first
        float xi = 0.f, xf = 0.f, xc = 0.f, xo = 0.f;
        if (tid < 128) {
            size_t rb = ((size_t)(t * 32 + b)) * GCOLS + n0 + cl;
            xi = bf2f(gates[rb]);
            xf = bf2f(gates[rb + 1024]);
            xc = bf2f(gates[rb + 2048]);
            xo = bf2f(gates[rb + 3072]);
        }

        // h fragments: 32 x 8B sc1 loads, all issued before the MFMA chain
        short8 a0[8], a1[8];
#pragma unroll
        for (int ks = 0; ks < 8; ++ks) {
            const ushort_t* hp = hc + arow * 1024 + kb + ks * 32 + ksub;
            union { u64 q[2]; short8 s; } u0l, u1l;
            u0l.q[0] = __hip_atomic_load((u64*)hp, __ATOMIC_RELAXED, __HIP_MEMORY_SCOPE_AGENT);
            u0l.q[1] = __hip_atomic_load((u64*)(hp + 4), __ATOMIC_RELAXED, __HIP_MEMORY_SCOPE_AGENT);
            u1l.q[0] = __hip_atomic_load((u64*)(hp + 16 * 1024), __ATOMIC_RELAXED, __HIP_MEMORY_SCOPE_AGENT);
            u1l.q[1] = __hip_atomic_load((u64*)(hp + 16 * 1024 + 4), __ATOMIC_RELAXED, __HIP_MEMORY_SCOPE_AGENT);
            a0[ks] = u0l.s;
            a1[ks] = u1l.s;
        }

        // GEMM: pre[b][j] = sum_k h[b,k] * V[j,k]
        f32x4 acc0 = {}, acc1 = {};
#pragma unroll
        for (int ks = 0; ks < 8; ++ks) {
            acc0 = __builtin_amdgcn_mfma_f32_16x16x32_bf16(a0[ks], bv[ks], acc0, 0, 0, 0);
            acc1 = __builtin_amdgcn_mfma_f32_16x16x32_bf16(a1[ks], bv[ks], acc1, 0, 0, 0);
        }
        {
            float* rp = red + wv * 512;
            int rr = (lane >> 4) * 4, rc = lane & 15;
#pragma unroll
            for (int r = 0; r < 4; ++r) {
                rp[(rr + r) * 16 + rc] = acc0[r];
                rp[256 + (rr + r) * 16 + rc] = acc1[r];
            }
        }
        __syncthreads();
        {
            float s0 = red[tid] + red[512 + tid] + red[1024 + tid] + red[1536 + tid];
            float s1 = red[256 + tid] + red[768 + tid] + red[1280 + tid] + red[1792 + tid];
            pre[tid] = s0;
            pre[256 + tid] = s1;
        }
        __syncthreads();

        if (tid < 128) {
            float pi = pre[b * 16 + cl];
            float pf = pre[b * 16 + 4 + cl];
            float pc = pre[b * 16 + 8 + cl];
            float po = pre[b * 16 + 12 + cl];
            float ig = sigmoidf_(xi + pi);
            float fg = sigmoidf_(xf + pf);
            float gg = tanhs_(xc + pc);
            float og = sigmoidf_(xo + po);
            c_reg = fg * c_reg + ig * gg;
            float h = og * tanhs_(c_reg);
            out[((size_t)t * 32 + b) * 1024 + n0 + cl] = h;
            hsh[tid] = f2bf(h);
            if (t == SEQ - 1) {
                out[HSEQ_ELEMS + b * 1024 + n0 + cl] = h;
                out[HSEQ_ELEMS + 32768 + b * 1024 + n0 + cl] = c_reg;
            }
        }
        __syncthreads();   // hsh ready
        // wave 0: publish h slice (sc1), drain own vmcnt, release flag, poll
        if (tid < 32) {
            u64 v = *(const u64*)&hsh[tid * 4];
            __hip_atomic_store((u64*)(hn + tid * 1024 + n0), v,
                               __ATOMIC_RELAXED, __HIP_MEMORY_SCOPE_AGENT);
        }
        if (wv == 0) {
            unsigned val = (unsigned)(t + 2);
            asm volatile("s_waitcnt vmcnt(0)" ::: "memory");
            if (lane == 0)
                __hip_atomic_store(&flags[w], val, __ATOMIC_RELAXED, __HIP_MEMORY_SCOPE_AGENT);
            for (;;) {
                unsigned f0 = __hip_atomic_load(&flags[lane], __ATOMIC_RELAXED, __HIP_MEMORY_SCOPE_AGENT);
                unsigned f1 = __hip_atomic_load(&flags[lane + 64], __ATOMIC_RELAXED, __HIP_MEMORY_SCOPE_AGENT);
                unsigned f2 = __hip_atomic_load(&flags[lane + 128], __ATOMIC_RELAXED, __HIP_MEMORY_SCOPE_AGENT);
                unsigned f3 = __hip_atomic_load(&flags[lane + 192], __ATOMIC_RELAXED, __HIP_MEMORY_SCOPE_AGENT);
                if (__all(f0 >= val && f1 >= val && f2 >= val && f3 >= val)) break;
                __builtin_amdgcn_s_sleep(1);
            }
        }
        __syncthreads();
    }
}

extern "C" void kernel_launch(void* const* d_in, const int* in_sizes, int n_in,
                              void* d_out, int out_size, void* d_ws, size_t ws_size,
                              hipStream_t stream) {
    const float* x  = (const float*)d_in[0];
    const float* Ui = (const float*)d_in[1];
    const float* Vi = (const float*)d_in[2];
    const float* bi = (const float*)d_in[3];
    const float* Uf = (const float*)d_in[4];
    const float* Vf = (const float*)d_in[5];
    const float* bfp= (const float*)d_in[6];
    const float* Uc = (const float*)d_in[7];
    const float* Vc = (const float*)d_in[8];
    const float* bc = (const float*)d_in[9];
    const float* Uo = (const float*)d_in[10];
    const float* Vo = (const float*)d_in[11];
    const float* bo = (const float*)d_in[12];

    char* ws = (char*)d_ws;
    unsigned* flags = (unsigned*)ws;                          // 4096 B
    ushort_t* hbuf  = (ushort_t*)(ws + 4096);                 // 131072 B (2 x 32x1024 bf16)
    ushort_t* xbf   = (ushort_t*)(ws + 135168);               // 33554432 B
    ushort_t* UT    = (ushort_t*)(ws + 33689600);             // 8388608 B
    ushort_t* VT    = (ushort_t*)(ws + 42078208);             // 8388608 B
    ushort_t* gates = (ushort_t*)(ws + 50466816);             // 134217728 B

    hipMemsetAsync(flags, 0, 4096, stream);
    hipLaunchKernelGGL(k_convert_x, dim3(8192), dim3(256), 0, stream, x, xbf);
    hipLaunchKernelGGL(k_transpose8, dim3(8192), dim3(256), 0, stream,
                       Ui, Uf, Uc, Uo, Vi, Vf, Vc, Vo, UT, VT);
    hipLaunchKernelGGL(k_gemm, dim3(4096), dim3(256), 0, stream,
                       xbf, UT, bi, bfp, bc, bo, gates);
    hipLaunchKernelGGL(k_scan, dim3(256), dim3(256), 0, stream,
                       gates, VT, hbuf, flags, (float*)d_out);
}